// Round 1
// baseline (263.845 us; speedup 1.0000x reference)
//
#include <hip/hip_runtime.h>

#define T_LEN 48000
#define NSEQ  1024
#define LC    400      // chunk length
#define KCH   120      // chunks per sequence
#define C0    40       // first chunk covering middle region
#define NMIDC 40       // chunks covering middle region

using short8 = __attribute__((ext_vector_type(8))) short;
using f32x4  = __attribute__((ext_vector_type(4))) float;

// ---------- channel filter constants (match reference numpy math, f64) ----------
__device__ __forceinline__ void chan_params(int ch, double& a1, double& a2, double& b0) {
    const double lf = log(10.0) + (double)ch * (log(100.0) - log(10.0)) / 63.0;
    const double f  = exp(lf);
    const double r  = 0.9999 + (double)ch * (0.99999 - 0.9999) / 63.0;
    const double th = 2.0 * 3.14159265358979323846 * f / 24000.0;
    a1 = -2.0 * r * cos(th);
    a2 = r * r;
    b0 = (1.0 - r) * 0.5;
}

__device__ __forceinline__ unsigned short f32_to_bf16(float f) {
    unsigned u = __float_as_uint(f);
    u += 0x7fffu + ((u >> 16) & 1u);     // round-to-nearest-even
    return (unsigned short)(u >> 16);
}

__device__ __forceinline__ float fast_tanh(float x) {
    const float e = __expf(2.0f * x);
    return 1.0f - 2.0f / (e + 1.0f);     // correct limits at +-inf
}

// ---------- zero accumulators (ws is poisoned 0xAA before every launch) ----------
__global__ void zero_kernel(double* acc) {
    if (threadIdx.x < 8) acc[threadIdx.x] = 0.0;
}

// ---------- MSS: one complex Stockham FFT per frame, pred+target packed ----------
template<int N, int HOP>
__global__ __launch_bounds__(256) void fft_mss_kernel(const float* __restrict__ pred,
                                                      const float* __restrict__ target,
                                                      double* __restrict__ acc, int accIdx) {
    __shared__ float2 bufA[N];
    __shared__ float2 bufB[N];
    __shared__ float red[256];
    const int tid = threadIdx.x;
    const int b   = blockIdx.x;
    const int fr  = blockIdx.y;
    const float* xp = pred   + b * T_LEN + fr * HOP;
    const float* xt = target + b * T_LEN + fr * HOP;

    for (int i = tid; i < N; i += 256) bufA[i] = make_float2(xp[i], xt[i]);
    __syncthreads();

    float2* X = bufA; float2* Y = bufB;
    int n = N, s = 1, ls = 0;
    while (n > 1) {
        const int m = n >> 1;
        const float w0 = -6.283185307179586f / (float)n;
        for (int i = tid; i < N / 2; i += 256) {
            const int p = i >> ls;               // i = p*s + q
            const float2 a  = X[i];
            const float2 bb = X[i + N / 2];
            float sn, cs;
            __sincosf(w0 * (float)p, &sn, &cs);  // e^{-2*pi*i*p/n}
            float2 e, o;
            e.x = a.x + bb.x;  e.y = a.y + bb.y;
            const float dr = a.x - bb.x, di = a.y - bb.y;
            o.x = dr * cs - di * sn;
            o.y = dr * sn + di * cs;
            const int o0 = i + s * p;            // q + 2*s*p
            Y[o0]     = e;
            Y[o0 + s] = o;
        }
        __syncthreads();
        float2* t2 = X; X = Y; Y = t2;
        n = m; s <<= 1; ls += 1;
    }

    // X = forward DFT of (pred + i*target), natural order. Split + magnitudes.
    float s1 = 0.f, s2 = 0.f;
    for (int k = tid; k <= N / 2; k += 256) {
        const int k2 = (N - k) & (N - 1);
        const float2 zk = X[k];
        const float2 zn = X[k2];
        const float xpr = 0.5f * (zk.x + zn.x), xpi = 0.5f * (zk.y - zn.y);
        const float xtr = 0.5f * (zk.y + zn.y), xti = 0.5f * (zn.x - zk.x);
        const float xm = sqrtf(xpr * xpr + xpi * xpi) + 1e-7f;
        const float ym = sqrtf(xtr * xtr + xti * xti) + 1e-7f;
        s1 += fabsf(xm - ym);
        s2 += fabsf(__logf(xm) - __logf(ym));
    }

    red[tid] = s1; __syncthreads();
    for (int off = 128; off > 0; off >>= 1) { if (tid < off) red[tid] += red[tid + off]; __syncthreads(); }
    const float bs1 = red[0];
    __syncthreads();
    red[tid] = s2; __syncthreads();
    for (int off = 128; off > 0; off >>= 1) { if (tid < off) red[tid] += red[tid + off]; __syncthreads(); }
    if (tid == 0) {
        atomicAdd(&acc[accIdx],     (double)bs1);
        atomicAdd(&acc[accIdx + 1], (double)red[0]);
    }
}

// ---------- l_raw ----------
__global__ __launch_bounds__(256) void raw_kernel(const float* __restrict__ pred,
                                                  const float* __restrict__ target,
                                                  double* __restrict__ acc) {
    __shared__ float red[256];
    const int i = blockIdx.x * 256 + threadIdx.x;    // exactly 64000 threads
    const int b = i / 16000;
    const int t = i - b * 16000 + 16000;
    red[threadIdx.x] = fabsf(pred[b * T_LEN + t] - target[b * T_LEN + t]);
    __syncthreads();
    for (int off = 128; off > 0; off >>= 1) { if (threadIdx.x < off) red[threadIdx.x] += red[threadIdx.x + off]; __syncthreads(); }
    if (threadIdx.x == 0) atomicAdd(&acc[7], (double)red[0]);
}

// ---------- IIR pass 1: per-chunk zero-init recurrence, store final state ----------
__global__ __launch_bounds__(256) void iir_pass1(const float* __restrict__ pred,
                                                 const float* __restrict__ target,
                                                 double2* __restrict__ P) {
    const int tid   = blockIdx.x * 256 + threadIdx.x;   // 1024*120
    const int seq   = tid & (NSEQ - 1);
    const int chunk = tid >> 10;
    const int ch  = seq & 63;
    const int dir = (seq >> 6) & 1;
    const int b   = (seq >> 7) & 3;
    const int sg  = seq >> 9;
    double a1, a2, b0; chan_params(ch, a1, a2, b0);
    const float* x = (sg ? target : pred) + b * T_LEN;
    const int n0   = chunk * LC;
    const int base = dir ? (T_LEN - 1 - n0) : n0;
    const int stp  = dir ? -1 : 1;
    double y1 = 0.0, y2 = 0.0;
    #pragma unroll 4
    for (int i = 0; i < LC; ++i) {
        const double xv = (double)x[base + stp * i];
        const double y  = b0 * xv - a1 * y1 - a2 * y2;
        y2 = y1; y1 = y;
    }
    P[chunk * NSEQ + seq] = make_double2(y1, y2);
}

// ---------- IIR combine: propagate 2x2 transition across chunks ----------
__global__ __launch_bounds__(256) void iir_combine(const double2* __restrict__ P,
                                                   double2* __restrict__ S) {
    const int seq = blockIdx.x * 256 + threadIdx.x;     // 1024 threads
    const int ch  = seq & 63;
    double a1, a2, b0; chan_params(ch, a1, a2, b0);
    // M = [[-a1,-a2],[1,0]]; Mc = M^LC by square-and-multiply (powers commute)
    double m00 = -a1, m01 = -a2, m10 = 1.0, m11 = 0.0;
    double r00 = 1.0, r01 = 0.0, r10 = 0.0, r11 = 1.0;
    int e = LC;
    while (e) {
        if (e & 1) {
            const double t00 = r00 * m00 + r01 * m10, t01 = r00 * m01 + r01 * m11;
            const double t10 = r10 * m00 + r11 * m10, t11 = r10 * m01 + r11 * m11;
            r00 = t00; r01 = t01; r10 = t10; r11 = t11;
        }
        const double q00 = m00 * m00 + m01 * m10, q01 = m00 * m01 + m01 * m11;
        const double q10 = m10 * m00 + m11 * m10, q11 = m10 * m01 + m11 * m11;
        m00 = q00; m01 = q01; m10 = q10; m11 = q11;
        e >>= 1;
    }
    double s1 = 0.0, s2 = 0.0;   // (y[-1], y[-2])
    #pragma unroll 4
    for (int i = 0; i < KCH; ++i) {
        S[i * NSEQ + seq] = make_double2(s1, s2);
        const double2 p = P[i * NSEQ + seq];
        const double n1 = r00 * s1 + r01 * s2 + p.x;
        const double n2 = r10 * s1 + r11 * s2 + p.y;
        s1 = n1; s2 = n2;
    }
}

// ---------- IIR pass 2: re-run middle chunks with correct init, emit bf16 H ----------
// H layout: H[((sg*4+b)*16000 + tm)*128 + (dir*64+ch)]  (lane=ch -> coalesced)
__global__ __launch_bounds__(256) void iir_pass2(const float* __restrict__ pred,
                                                 const float* __restrict__ target,
                                                 const double2* __restrict__ S,
                                                 unsigned short* __restrict__ H) {
    const int tid   = blockIdx.x * 256 + threadIdx.x;   // 1024*40
    const int seq   = tid & (NSEQ - 1);
    const int chunk = C0 + (tid >> 10);
    const int ch  = seq & 63;
    const int dir = (seq >> 6) & 1;
    const int b   = (seq >> 7) & 3;
    const int sg  = seq >> 9;
    double a1, a2, b0; chan_params(ch, a1, a2, b0);
    const float* x = (sg ? target : pred) + b * T_LEN;
    const double2 st = S[chunk * NSEQ + seq];
    double y1 = st.x, y2 = st.y;
    const int n0 = chunk * LC;
    unsigned short* Hb = H + (size_t)(sg * 4 + b) * 16000 * 128 + (dir * 64 + ch);
    #pragma unroll 2
    for (int i = 0; i < LC; ++i) {
        const int n = n0 + i;
        const double xv = (double)x[dir ? (T_LEN - 1 - n) : n];
        const double y  = b0 * xv - a1 * y1 - a2 * y2;
        const int tm = dir ? (31999 - n) : (n - 16000);
        Hb[(size_t)tm * 128] = f32_to_bf16((float)y);
        y2 = y1; y1 = y;
    }
}

// ---------- embedding GEMM (MFMA bf16) + tanh + |diff| reduction ----------
// per wave: one n-tile (16 t's) for all 4 b, full M=64, both signals
__global__ __launch_bounds__(256) void embed_kernel(const float* __restrict__ W,
                                                    const unsigned short* __restrict__ H,
                                                    double* __restrict__ acc) {
    const int lane = threadIdx.x & 63;
    const int wave = threadIdx.x >> 6;
    const int gw   = blockIdx.x * 4 + wave;      // 0..999 = n-tile index
    const int row  = lane & 15;
    const int quad = lane >> 4;

    // A fragments: W[o][c] bf16, A[m=lane&15][k=quad*8+j]; reused across tiles
    short8 A[4][4];
    #pragma unroll
    for (int mi = 0; mi < 4; ++mi)
        #pragma unroll
        for (int ki = 0; ki < 4; ++ki) {
            const float* wp = W + (mi * 16 + row) * 128 + ki * 32 + quad * 8;
            short8 a;
            #pragma unroll
            for (int j = 0; j < 8; ++j) a[j] = (short)f32_to_bf16(wp[j]);
            A[mi][ki] = a;
        }

    float lsum = 0.f;
    const int t0 = gw * 16;
    for (int b = 0; b < 4; ++b) {
        // B fragment: B[k][n] = H[t0+n][k], n=lane&15, k=quad*8+j (16B contiguous)
        const unsigned short* hp = H + (size_t)(b * 16000 + t0 + row) * 128 + quad * 8;
        const unsigned short* ht = hp + (size_t)4 * 16000 * 128;
        f32x4 accp[4], acct[4];
        #pragma unroll
        for (int mi = 0; mi < 4; ++mi) {
            accp[mi] = f32x4{0.f, 0.f, 0.f, 0.f};
            acct[mi] = f32x4{0.f, 0.f, 0.f, 0.f};
        }
        #pragma unroll
        for (int ki = 0; ki < 4; ++ki) {
            const short8 bp = *(const short8*)(hp + ki * 32);
            const short8 bt = *(const short8*)(ht + ki * 32);
            #pragma unroll
            for (int mi = 0; mi < 4; ++mi) {
                accp[mi] = __builtin_amdgcn_mfma_f32_16x16x32_bf16(A[mi][ki], bp, accp[mi], 0, 0, 0);
                acct[mi] = __builtin_amdgcn_mfma_f32_16x16x32_bf16(A[mi][ki], bt, acct[mi], 0, 0, 0);
            }
        }
        #pragma unroll
        for (int mi = 0; mi < 4; ++mi)
            #pragma unroll
            for (int r = 0; r < 4; ++r) {
                const float ep = fast_tanh(accp[mi][r]);
                const float et = fast_tanh(acct[mi][r]);
                lsum += fabsf(ep - et);
            }
    }
    for (int off = 32; off >= 1; off >>= 1) lsum += __shfl_down(lsum, off, 64);
    if (lane == 0) atomicAdd(&acc[6], (double)lsum);
}

// ---------- finalize ----------
__global__ void finalize_kernel(const double* __restrict__ acc, float* __restrict__ out) {
    if (threadIdx.x == 0 && blockIdx.x == 0) {
        double lm = (acc[0] + acc[1]) / (4.0 * 372.0 * 257.0);
        lm       += (acc[2] + acc[3]) / (4.0 * 184.0 * 513.0);
        lm       += (acc[4] + acc[5]) / (4.0 * 90.0 * 1025.0);
        const double la = acc[6] / (4.0 * 64.0 * 16000.0);
        const double lr = acc[7] / 64000.0 * 0.1;
        out[0] = (float)(lm + 10.0 * la + lr);
        out[1] = (float)lm;
        out[2] = (float)la;
    }
}

extern "C" void kernel_launch(void* const* d_in, const int* in_sizes, int n_in,
                              void* d_out, int out_size, void* d_ws, size_t ws_size,
                              hipStream_t stream) {
    const float* pred   = (const float*)d_in[0];
    const float* target = (const float*)d_in[1];
    const float* W      = (const float*)d_in[2];
    float* out = (float*)d_out;

    // workspace layout (all 16B aligned)
    double*  acc = (double*)d_ws;                                     // 8 doubles
    double2* P   = (double2*)((char*)d_ws + 256);                     // 120*1024*16 B
    double2* S   = (double2*)((char*)d_ws + 256 + 1966080);           // 120*1024*16 B
    unsigned short* H = (unsigned short*)((char*)d_ws + 256 + 2 * 1966080); // 32.77 MB

    hipLaunchKernelGGL(zero_kernel, dim3(1), dim3(64), 0, stream, acc);
    hipLaunchKernelGGL((fft_mss_kernel<512, 128>),  dim3(4, 372), dim3(256), 0, stream, pred, target, acc, 0);
    hipLaunchKernelGGL((fft_mss_kernel<1024, 256>), dim3(4, 184), dim3(256), 0, stream, pred, target, acc, 2);
    hipLaunchKernelGGL((fft_mss_kernel<2048, 512>), dim3(4, 90),  dim3(256), 0, stream, pred, target, acc, 4);
    hipLaunchKernelGGL(raw_kernel,  dim3(250), dim3(256), 0, stream, pred, target, acc);
    hipLaunchKernelGGL(iir_pass1,   dim3(480), dim3(256), 0, stream, pred, target, P);
    hipLaunchKernelGGL(iir_combine, dim3(4),   dim3(256), 0, stream, P, S);
    hipLaunchKernelGGL(iir_pass2,   dim3(160), dim3(256), 0, stream, pred, target, S, H);
    hipLaunchKernelGGL(embed_kernel, dim3(250), dim3(256), 0, stream, W, H, acc);
    hipLaunchKernelGGL(finalize_kernel, dim3(1), dim3(1), 0, stream, acc, out);
}

// Round 2
// 202.202 us; speedup vs baseline: 1.3049x; 1.3049x over previous
//
#include <hip/hip_runtime.h>

#define T_LEN 48000
#define NSEQ  1024
#define LC    100      // chunk length
#define NCHK  320      // chunks 0..319 cover samples [0,32000) in traversal order
#define GRP   16       // chunks per scan group
#define NGRP  20       // groups

using short8 = __attribute__((ext_vector_type(8))) short;
using f32x4  = __attribute__((ext_vector_type(4))) float;

// ---------- channel filter constants (match reference numpy math, f64) ----------
__device__ __forceinline__ void chan_params(int ch, double& a1, double& a2, double& b0) {
    const double lf = log(10.0) + (double)ch * (log(100.0) - log(10.0)) / 63.0;
    const double f  = exp(lf);
    const double r  = 0.9999 + (double)ch * (0.99999 - 0.9999) / 63.0;
    const double th = 2.0 * 3.14159265358979323846 * f / 24000.0;
    a1 = -2.0 * r * cos(th);
    a2 = r * r;
    b0 = (1.0 - r) * 0.5;
}

__device__ __forceinline__ unsigned short f32_to_bf16(float f) {
    unsigned u = __float_as_uint(f);
    u += 0x7fffu + ((u >> 16) & 1u);     // round-to-nearest-even
    return (unsigned short)(u >> 16);
}

__device__ __forceinline__ float fast_tanh(float x) {
    const float e = __expf(2.0f * x);
    return 1.0f - 2.0f / (e + 1.0f);     // correct limits at +-inf
}

// ---------- setup: zero accumulators + per-channel constant table ----------
// cst[ch*16 + {0,1,2}] = a1,a2,b0 ; {3..6} = A = M^LC ; {7..10} = A16 = A^GRP
__global__ void setup_kernel(double* __restrict__ cst, double* __restrict__ acc) {
    const int t = threadIdx.x;
    if (t < 8) acc[t] = 0.0;
    if (t < 64) {
        double a1, a2, b0; chan_params(t, a1, a2, b0);
        double m00 = -a1, m01 = -a2, m10 = 1.0, m11 = 0.0;
        double r00 = 1.0, r01 = 0.0, r10 = 0.0, r11 = 1.0;
        int e = LC;
        while (e) {
            if (e & 1) {
                const double t00 = r00 * m00 + r01 * m10, t01 = r00 * m01 + r01 * m11;
                const double t10 = r10 * m00 + r11 * m10, t11 = r10 * m01 + r11 * m11;
                r00 = t00; r01 = t01; r10 = t10; r11 = t11;
            }
            const double q00 = m00 * m00 + m01 * m10, q01 = m00 * m01 + m01 * m11;
            const double q10 = m10 * m00 + m11 * m10, q11 = m10 * m01 + m11 * m11;
            m00 = q00; m01 = q01; m10 = q10; m11 = q11;
            e >>= 1;
        }
        cst[t * 16 + 0] = a1; cst[t * 16 + 1] = a2; cst[t * 16 + 2] = b0;
        cst[t * 16 + 3] = r00; cst[t * 16 + 4] = r01;
        cst[t * 16 + 5] = r10; cst[t * 16 + 6] = r11;
        double q00 = r00, q01 = r01, q10 = r10, q11 = r11;
        #pragma unroll
        for (int s = 0; s < 4; ++s) {   // A^16 via 4 squarings
            const double n00 = q00 * q00 + q01 * q10, n01 = q00 * q01 + q01 * q11;
            const double n10 = q10 * q00 + q11 * q10, n11 = q10 * q01 + q11 * q11;
            q00 = n00; q01 = n01; q10 = n10; q11 = n11;
        }
        cst[t * 16 + 7] = q00; cst[t * 16 + 8]  = q01;
        cst[t * 16 + 9] = q10; cst[t * 16 + 10] = q11;
    }
}

// ---------- MSS: all 3 STFT configs in one kernel; complex-packed Stockham ----------
__global__ __launch_bounds__(256) void fft_mss_all(const float* __restrict__ pred,
                                                   const float* __restrict__ target,
                                                   double* __restrict__ acc) {
    __shared__ float2 bufA[2048];
    __shared__ float2 bufB[2048];
    __shared__ float red[256];
    const int blk = blockIdx.x;
    int N, HOP, accIdx, id;
    if (blk < 1488)      { N = 512;  HOP = 128; accIdx = 0; id = blk; }
    else if (blk < 2224) { N = 1024; HOP = 256; accIdx = 2; id = blk - 1488; }
    else                 { N = 2048; HOP = 512; accIdx = 4; id = blk - 2224; }
    const int tid = threadIdx.x;
    const int b   = id & 3;
    const int fr  = id >> 2;
    const float* xp = pred   + b * T_LEN + fr * HOP;
    const float* xt = target + b * T_LEN + fr * HOP;

    for (int i = tid; i < N; i += 256) bufA[i] = make_float2(xp[i], xt[i]);
    __syncthreads();

    float2* X = bufA; float2* Y = bufB;
    int n = N, s = 1, ls = 0;
    while (n > 1) {
        const float w0 = -6.283185307179586f / (float)n;
        for (int i = tid; i < (N >> 1); i += 256) {
            const int p = i >> ls;               // i = p*s + q
            const float2 a  = X[i];
            const float2 bb = X[i + (N >> 1)];
            float sn, cs;
            __sincosf(w0 * (float)p, &sn, &cs);  // e^{-2*pi*i*p/n}
            float2 e, o;
            e.x = a.x + bb.x;  e.y = a.y + bb.y;
            const float dr = a.x - bb.x, di = a.y - bb.y;
            o.x = dr * cs - di * sn;
            o.y = dr * sn + di * cs;
            const int o0 = i + s * p;            // q + 2*s*p
            Y[o0]     = e;
            Y[o0 + s] = o;
        }
        __syncthreads();
        float2* t2 = X; X = Y; Y = t2;
        n >>= 1; s <<= 1; ls += 1;
    }

    // X = DFT of (pred + i*target), natural order. Split + magnitudes.
    float s1 = 0.f, s2 = 0.f;
    for (int k = tid; k <= (N >> 1); k += 256) {
        const int k2 = (N - k) & (N - 1);
        const float2 zk = X[k];
        const float2 zn = X[k2];
        const float xpr = 0.5f * (zk.x + zn.x), xpi = 0.5f * (zk.y - zn.y);
        const float xtr = 0.5f * (zk.y + zn.y), xti = 0.5f * (zn.x - zk.x);
        const float xm = sqrtf(xpr * xpr + xpi * xpi) + 1e-7f;
        const float ym = sqrtf(xtr * xtr + xti * xti) + 1e-7f;
        s1 += fabsf(xm - ym);
        s2 += fabsf(__logf(xm) - __logf(ym));
    }

    red[tid] = s1; __syncthreads();
    for (int off = 128; off > 0; off >>= 1) { if (tid < off) red[tid] += red[tid + off]; __syncthreads(); }
    const float bs1 = red[0];
    __syncthreads();
    red[tid] = s2; __syncthreads();
    for (int off = 128; off > 0; off >>= 1) { if (tid < off) red[tid] += red[tid + off]; __syncthreads(); }
    if (tid == 0) {
        atomicAdd(&acc[accIdx],     (double)bs1);
        atomicAdd(&acc[accIdx + 1], (double)red[0]);
    }
}

// ---------- IIR pass 1: per-chunk zero-init recurrence over chunks 0..NCHK-1 ----------
__global__ __launch_bounds__(256) void iir_pass1(const float* __restrict__ pred,
                                                 const float* __restrict__ target,
                                                 const double* __restrict__ cst,
                                                 float2* __restrict__ P) {
    const int tid   = blockIdx.x * 256 + threadIdx.x;   // NCHK*1024
    const int seq   = tid & (NSEQ - 1);
    const int chunk = tid >> 10;
    const int ch  = seq & 63;
    const int dir = (seq >> 6) & 1;
    const int b   = (seq >> 7) & 3;
    const int sg  = seq >> 9;
    const double a1 = cst[ch * 16 + 0], a2 = cst[ch * 16 + 1], b0 = cst[ch * 16 + 2];
    const float* x = (sg ? target : pred) + b * T_LEN;
    const int n0   = chunk * LC;
    const int base = dir ? (T_LEN - 1 - n0) : n0;
    const int stp  = dir ? -1 : 1;
    double y1 = 0.0, y2 = 0.0;
    #pragma unroll 4
    for (int i = 0; i < LC; ++i) {
        const double xv = (double)x[base + stp * i];
        const double y  = b0 * xv - a1 * y1 - a2 * y2;
        y2 = y1; y1 = y;
    }
    P[chunk * NSEQ + seq] = make_float2((float)y1, (float)y2);
}

// ---------- scan level A: group totals (affine offset of 16 chunks, zero init) ----------
__global__ __launch_bounds__(256) void iir_scanA(const double* __restrict__ cst,
                                                 const float2* __restrict__ P,
                                                 float2* __restrict__ Tg) {
    const int tid = blockIdx.x * 256 + threadIdx.x;     // NGRP*1024
    const int seq = tid & (NSEQ - 1);
    const int g   = tid >> 10;
    const int ch  = seq & 63;
    const double A00 = cst[ch * 16 + 3], A01 = cst[ch * 16 + 4];
    const double A10 = cst[ch * 16 + 5], A11 = cst[ch * 16 + 6];
    double t1 = 0.0, t2 = 0.0;
    #pragma unroll
    for (int j = 0; j < GRP; ++j) {
        const float2 p = P[(g * GRP + j) * NSEQ + seq];
        const double n1 = A00 * t1 + A01 * t2 + (double)p.x;
        const double n2 = A10 * t1 + A11 * t2 + (double)p.y;
        t1 = n1; t2 = n2;
    }
    Tg[g * NSEQ + seq] = make_float2((float)t1, (float)t2);
}

// ---------- scan level B: exclusive prefix over groups ----------
__global__ __launch_bounds__(256) void iir_scanB(const double* __restrict__ cst,
                                                 const float2* __restrict__ Tg,
                                                 float2* __restrict__ G) {
    const int seq = blockIdx.x * 256 + threadIdx.x;     // 1024
    const int ch  = seq & 63;
    const double B00 = cst[ch * 16 + 7], B01 = cst[ch * 16 + 8];
    const double B10 = cst[ch * 16 + 9], B11 = cst[ch * 16 + 10];
    double g1 = 0.0, g2 = 0.0;
    #pragma unroll
    for (int g = 0; g < NGRP; ++g) {
        G[g * NSEQ + seq] = make_float2((float)g1, (float)g2);
        const float2 t = Tg[g * NSEQ + seq];
        const double n1 = B00 * g1 + B01 * g2 + (double)t.x;
        const double n2 = B10 * g1 + B11 * g2 + (double)t.y;
        g1 = n1; g2 = n2;
    }
}

// ---------- IIR pass 2: fixup from group prefix, then emit bf16 H for middle ----------
// H layout: H[((sg*4+b)*16000 + tm)*128 + (dir*64+ch)]
__global__ __launch_bounds__(256) void iir_pass2(const float* __restrict__ pred,
                                                 const float* __restrict__ target,
                                                 const double* __restrict__ cst,
                                                 const float2* __restrict__ P,
                                                 const float2* __restrict__ G,
                                                 unsigned short* __restrict__ H) {
    const int tid = blockIdx.x * 256 + threadIdx.x;     // 160*1024
    const int seq = tid & (NSEQ - 1);
    const int c   = 160 + (tid >> 10);                  // chunks 160..319
    const int ch  = seq & 63;
    const int dir = (seq >> 6) & 1;
    const int b   = (seq >> 7) & 3;
    const int sg  = seq >> 9;
    const double a1 = cst[ch * 16 + 0], a2 = cst[ch * 16 + 1], b0 = cst[ch * 16 + 2];
    const double A00 = cst[ch * 16 + 3], A01 = cst[ch * 16 + 4];
    const double A10 = cst[ch * 16 + 5], A11 = cst[ch * 16 + 6];
    const int g = c >> 4;
    const float2 gs = G[g * NSEQ + seq];
    double y1 = (double)gs.x, y2 = (double)gs.y;
    for (int k = g * GRP; k < c; ++k) {                 // <= 15 affine fixup steps
        const float2 p = P[k * NSEQ + seq];
        const double n1 = A00 * y1 + A01 * y2 + (double)p.x;
        const double n2 = A10 * y1 + A11 * y2 + (double)p.y;
        y1 = n1; y2 = n2;
    }
    const float* x = (sg ? target : pred) + b * T_LEN;
    const int n0 = c * LC;
    unsigned short* Hb = H + (size_t)(sg * 4 + b) * 16000 * 128 + (dir * 64 + ch);
    if (dir == 0) {
        #pragma unroll 4
        for (int i = 0; i < LC; ++i) {
            const int n = n0 + i;
            const double xv = (double)x[n];
            const double y  = b0 * xv - a1 * y1 - a2 * y2;
            Hb[(size_t)(n - 16000) * 128] = f32_to_bf16((float)y);
            y2 = y1; y1 = y;
        }
    } else {
        #pragma unroll 4
        for (int i = 0; i < LC; ++i) {
            const int n = n0 + i;
            const double xv = (double)x[T_LEN - 1 - n];
            const double y  = b0 * xv - a1 * y1 - a2 * y2;
            Hb[(size_t)(31999 - n) * 128] = f32_to_bf16((float)y);
            y2 = y1; y1 = y;
        }
    }
}

// ---------- embedding GEMM (MFMA bf16) + tanh + |diff| reduction; l_raw folded in ----------
__global__ __launch_bounds__(256) void embed_kernel(const float* __restrict__ W,
                                                    const unsigned short* __restrict__ H,
                                                    const float* __restrict__ pred,
                                                    const float* __restrict__ target,
                                                    double* __restrict__ acc) {
    // l_raw: grid is exactly 250*256 = 64000 threads
    {
        const int i  = blockIdx.x * 256 + threadIdx.x;
        const int bb = i / 16000;
        const int t  = i - bb * 16000 + 16000;
        float r = fabsf(pred[bb * T_LEN + t] - target[bb * T_LEN + t]);
        for (int off = 32; off >= 1; off >>= 1) r += __shfl_down(r, off, 64);
        if ((threadIdx.x & 63) == 0) atomicAdd(&acc[7], (double)r);
    }

    const int lane = threadIdx.x & 63;
    const int wave = threadIdx.x >> 6;
    const int gw   = blockIdx.x * 4 + wave;      // 0..999 = n-tile index
    const int row  = lane & 15;
    const int quad = lane >> 4;

    // A fragments: W[o][c] bf16, A[m=lane&15][k=quad*8+j]
    short8 A[4][4];
    #pragma unroll
    for (int mi = 0; mi < 4; ++mi)
        #pragma unroll
        for (int ki = 0; ki < 4; ++ki) {
            const float* wp = W + (mi * 16 + row) * 128 + ki * 32 + quad * 8;
            short8 a;
            #pragma unroll
            for (int j = 0; j < 8; ++j) a[j] = (short)f32_to_bf16(wp[j]);
            A[mi][ki] = a;
        }

    float lsum = 0.f;
    const int t0 = gw * 16;
    for (int b = 0; b < 4; ++b) {
        const unsigned short* hp = H + (size_t)(b * 16000 + t0 + row) * 128 + quad * 8;
        const unsigned short* ht = hp + (size_t)4 * 16000 * 128;
        f32x4 accp[4], acct[4];
        #pragma unroll
        for (int mi = 0; mi < 4; ++mi) {
            accp[mi] = f32x4{0.f, 0.f, 0.f, 0.f};
            acct[mi] = f32x4{0.f, 0.f, 0.f, 0.f};
        }
        #pragma unroll
        for (int ki = 0; ki < 4; ++ki) {
            const short8 bp = *(const short8*)(hp + ki * 32);
            const short8 bt = *(const short8*)(ht + ki * 32);
            #pragma unroll
            for (int mi = 0; mi < 4; ++mi) {
                accp[mi] = __builtin_amdgcn_mfma_f32_16x16x32_bf16(A[mi][ki], bp, accp[mi], 0, 0, 0);
                acct[mi] = __builtin_amdgcn_mfma_f32_16x16x32_bf16(A[mi][ki], bt, acct[mi], 0, 0, 0);
            }
        }
        #pragma unroll
        for (int mi = 0; mi < 4; ++mi)
            #pragma unroll
            for (int r = 0; r < 4; ++r) {
                const float ep = fast_tanh(accp[mi][r]);
                const float et = fast_tanh(acct[mi][r]);
                lsum += fabsf(ep - et);
            }
    }
    for (int off = 32; off >= 1; off >>= 1) lsum += __shfl_down(lsum, off, 64);
    if (lane == 0) atomicAdd(&acc[6], (double)lsum);
}

// ---------- finalize ----------
__global__ void finalize_kernel(const double* __restrict__ acc, float* __restrict__ out) {
    if (threadIdx.x == 0 && blockIdx.x == 0) {
        double lm = (acc[0] + acc[1]) / (4.0 * 372.0 * 257.0);
        lm       += (acc[2] + acc[3]) / (4.0 * 184.0 * 513.0);
        lm       += (acc[4] + acc[5]) / (4.0 * 90.0 * 1025.0);
        const double la = acc[6] / (4.0 * 64.0 * 16000.0);
        const double lr = acc[7] / 64000.0 * 0.1;
        out[0] = (float)(lm + 10.0 * la + lr);
        out[1] = (float)lm;
        out[2] = (float)la;
    }
}

extern "C" void kernel_launch(void* const* d_in, const int* in_sizes, int n_in,
                              void* d_out, int out_size, void* d_ws, size_t ws_size,
                              hipStream_t stream) {
    const float* pred   = (const float*)d_in[0];
    const float* target = (const float*)d_in[1];
    const float* W      = (const float*)d_in[2];
    float* out = (float*)d_out;

    // workspace layout (16B aligned), total ~35.7 MB
    char* ws = (char*)d_ws;
    double*  acc = (double*)ws;                               // 64 B
    double*  cst = (double*)(ws + 256);                       // 64*16*8 = 8192 B
    float2*  P   = (float2*)(ws + 16384);                     // 320*1024*8 = 2,621,440 B
    float2*  Tg  = (float2*)(ws + 2637824);                   // 20*1024*8 = 163,840 B
    float2*  G   = (float2*)(ws + 2801664);                   // 20*1024*8 = 163,840 B
    unsigned short* H = (unsigned short*)(ws + 2965504);      // 8*16000*128*2 = 32,768,000 B

    hipLaunchKernelGGL(setup_kernel, dim3(1), dim3(64), 0, stream, cst, acc);
    hipLaunchKernelGGL(fft_mss_all, dim3(2584), dim3(256), 0, stream, pred, target, acc);
    hipLaunchKernelGGL(iir_pass1,   dim3(NCHK * 4), dim3(256), 0, stream, pred, target, cst, P);
    hipLaunchKernelGGL(iir_scanA,   dim3(NGRP * 4), dim3(256), 0, stream, cst, P, Tg);
    hipLaunchKernelGGL(iir_scanB,   dim3(4), dim3(256), 0, stream, cst, Tg, G);
    hipLaunchKernelGGL(iir_pass2,   dim3(640), dim3(256), 0, stream, pred, target, cst, P, G, H);
    hipLaunchKernelGGL(embed_kernel, dim3(250), dim3(256), 0, stream, W, H, pred, target, acc);
    hipLaunchKernelGGL(finalize_kernel, dim3(1), dim3(1), 0, stream, acc, out);
}

// Round 3
// 197.435 us; speedup vs baseline: 1.3364x; 1.0241x over previous
//
#include <hip/hip_runtime.h>

#define T_LEN 48000
#define NSEQ  1024
#define LC    100      // chunk length
#define NCHK  320      // chunks 0..319 cover samples [0,32000) in traversal order
#define GRP   16       // chunks per scan group
#define NGRP  20       // groups

#define NB_F2048 360
#define NB_F1024 736
#define NB_F512  1488
#define NB_FFT   2584
#define NB_P1    1280  // NCHK*1024/256

using short8 = __attribute__((ext_vector_type(8))) short;
using f32x4  = __attribute__((ext_vector_type(4))) float;

// ---------- channel filter constants (match reference numpy math, f64) ----------
__device__ __forceinline__ void chan_params(int ch, double& a1, double& a2, double& b0) {
    const double lf = log(10.0) + (double)ch * (log(100.0) - log(10.0)) / 63.0;
    const double f  = exp(lf);
    const double r  = 0.9999 + (double)ch * (0.99999 - 0.9999) / 63.0;
    const double th = 2.0 * 3.14159265358979323846 * f / 24000.0;
    a1 = -2.0 * r * cos(th);
    a2 = r * r;
    b0 = (1.0 - r) * 0.5;
}

__device__ __forceinline__ unsigned short f32_to_bf16(float f) {
    unsigned u = __float_as_uint(f);
    u += 0x7fffu + ((u >> 16) & 1u);     // round-to-nearest-even
    return (unsigned short)(u >> 16);
}

__device__ __forceinline__ float fast_tanh(float x) {
    const float e = __expf(2.0f * x);
    return 1.0f - 2.0f / (e + 1.0f);
}

__device__ __forceinline__ float2 cmul(float2 a, float2 b) {
    return make_float2(a.x * b.x - a.y * b.y, a.x * b.y + a.y * b.x);
}
__device__ __forceinline__ float2 cadd(float2 a, float2 b) { return make_float2(a.x + b.x, a.y + b.y); }
__device__ __forceinline__ float2 csub(float2 a, float2 b) { return make_float2(a.x - b.x, a.y - b.y); }

// ---------- setup: zero accumulators + per-channel constant table ----------
// cst[ch*16 + {0,1,2}] = a1,a2,b0 ; {3..6} = A = M^LC ; {7..10} = A16 = A^GRP
__global__ void setup_kernel(double* __restrict__ cst, double* __restrict__ acc) {
    const int t = threadIdx.x;
    if (t < 8) acc[t] = 0.0;
    if (t < 64) {
        double a1, a2, b0; chan_params(t, a1, a2, b0);
        double m00 = -a1, m01 = -a2, m10 = 1.0, m11 = 0.0;
        double r00 = 1.0, r01 = 0.0, r10 = 0.0, r11 = 1.0;
        int e = LC;
        while (e) {
            if (e & 1) {
                const double t00 = r00 * m00 + r01 * m10, t01 = r00 * m01 + r01 * m11;
                const double t10 = r10 * m00 + r11 * m10, t11 = r10 * m01 + r11 * m11;
                r00 = t00; r01 = t01; r10 = t10; r11 = t11;
            }
            const double q00 = m00 * m00 + m01 * m10, q01 = m00 * m01 + m01 * m11;
            const double q10 = m10 * m00 + m11 * m10, q11 = m10 * m01 + m11 * m11;
            m00 = q00; m01 = q01; m10 = q10; m11 = q11;
            e >>= 1;
        }
        cst[t * 16 + 0] = a1; cst[t * 16 + 1] = a2; cst[t * 16 + 2] = b0;
        cst[t * 16 + 3] = r00; cst[t * 16 + 4] = r01;
        cst[t * 16 + 5] = r10; cst[t * 16 + 6] = r11;
        double q00 = r00, q01 = r01, q10 = r10, q11 = r11;
        #pragma unroll
        for (int s = 0; s < 4; ++s) {   // A^16 via 4 squarings
            const double n00 = q00 * q00 + q01 * q10, n01 = q00 * q01 + q01 * q11;
            const double n10 = q10 * q00 + q11 * q10, n11 = q10 * q01 + q11 * q11;
            q00 = n00; q01 = n01; q10 = n10; q11 = n11;
        }
        cst[t * 16 + 7] = q00; cst[t * 16 + 8]  = q01;
        cst[t * 16 + 9] = q10; cst[t * 16 + 10] = q11;
    }
}

// ---------- phase1: FFT/MSS blocks (heavy N first) + iir_pass1 blocks ----------
__global__ __launch_bounds__(256) void phase1_kernel(const float* __restrict__ pred,
                                                     const float* __restrict__ target,
                                                     const double* __restrict__ cst,
                                                     float2* __restrict__ P,
                                                     double* __restrict__ acc) {
    __shared__ float2 bufA[2048];
    __shared__ float2 bufB[2048];
    __shared__ float2 twl[512];     // tw[k] = exp(-2*pi*i*k/N), k < N/4
    __shared__ float redw[8];
    const int blk = blockIdx.x;

    if (blk < NB_FFT) {
        int N, HOP, accIdx, id;
        if (blk < NB_F2048)                  { N = 2048; HOP = 512; accIdx = 4; id = blk; }
        else if (blk < NB_F2048 + NB_F1024)  { N = 1024; HOP = 256; accIdx = 2; id = blk - NB_F2048; }
        else                                 { N = 512;  HOP = 128; accIdx = 0; id = blk - NB_F2048 - NB_F1024; }
        const int tid = threadIdx.x;
        const int b   = id & 3;
        const int fr  = id >> 2;
        const int N4  = N >> 2;
        const float* xp = pred   + b * T_LEN + fr * HOP;
        const float* xt = target + b * T_LEN + fr * HOP;

        const float wstep = -6.283185307179586f / (float)N;
        for (int k = tid; k < N4; k += 256) {
            float sn, cs; __sincosf(wstep * (float)k, &sn, &cs);
            twl[k] = make_float2(cs, sn);
        }
        for (int i = tid; i < N; i += 256) bufA[i] = make_float2(xp[i], xt[i]);
        __syncthreads();

        float2* X = bufA; float2* Y = bufB;
        int s = 1, ls = 0;
        while ((s << 2) <= N) {                    // fused radix-4 stage
            for (int i = tid; i < N4; i += 256) {
                const int p  = i >> ls;
                const int q  = i & (s - 1);
                const int k1 = p << ls;            // s*p < N/4
                const float2 a0 = X[i];
                const float2 a1 = X[i + N4];
                const float2 a2 = X[i + 2 * N4];
                const float2 a3 = X[i + 3 * N4];
                const float2 w1 = twl[k1];
                const int   k2 = k1 << 1;          // 2*s*p < N/2
                const float2 t2 = twl[k2 & (N4 - 1)];
                const float2 w2 = (k2 < N4) ? t2 : make_float2(t2.y, -t2.x);
                const float2 e1 = cadd(a0, a2), d1 = csub(a0, a2);
                const float2 e2 = cadd(a1, a3), d2 = csub(a1, a3);
                const float2 o1 = cmul(d1, w1);
                const float2 ot = cmul(d2, w1);
                const float2 o2 = make_float2(ot.y, -ot.x);      // * (-i)
                const float2 E1 = cadd(e1, e2);
                const float2 O1 = cmul(csub(e1, e2), w2);
                const float2 E2 = cadd(o1, o2);
                const float2 O2 = cmul(csub(o1, o2), w2);
                const int o4 = q + (p << (ls + 2));               // q + 4*s*p
                Y[o4]         = E1;
                Y[o4 + s]     = E2;
                Y[o4 + 2 * s] = O1;
                Y[o4 + 3 * s] = O2;
            }
            __syncthreads();
            float2* t = X; X = Y; Y = t;
            s <<= 2; ls += 2;
        }
        if (s < N) {                                // final radix-2 (s == N/2), tw = 1
            const int half = N >> 1;
            for (int i = tid; i < half; i += 256) {
                const float2 a = X[i], c = X[i + half];
                Y[i]        = cadd(a, c);
                Y[i + half] = csub(a, c);
            }
            __syncthreads();
            float2* t = X; X = Y; Y = t;
        }

        // X = DFT of (pred + i*target), natural order. Split + magnitudes.
        float s1 = 0.f, s2 = 0.f;
        for (int k = tid; k <= (N >> 1); k += 256) {
            const int k2 = (N - k) & (N - 1);
            const float2 zk = X[k];
            const float2 zn = X[k2];
            const float xpr = 0.5f * (zk.x + zn.x), xpi = 0.5f * (zk.y - zn.y);
            const float xtr = 0.5f * (zk.y + zn.y), xti = 0.5f * (zn.x - zk.x);
            const float xm = sqrtf(xpr * xpr + xpi * xpi) + 1e-7f;
            const float ym = sqrtf(xtr * xtr + xti * xti) + 1e-7f;
            s1 += fabsf(xm - ym);
            s2 += fabsf(__logf(xm) - __logf(ym));
        }
        for (int off = 32; off >= 1; off >>= 1) {
            s1 += __shfl_down(s1, off, 64);
            s2 += __shfl_down(s2, off, 64);
        }
        const int lane = tid & 63, wv = tid >> 6;
        if (lane == 0) { redw[wv] = s1; redw[wv + 4] = s2; }
        __syncthreads();
        if (tid == 0) {
            atomicAdd(&acc[accIdx],     (double)(redw[0] + redw[1] + redw[2] + redw[3]));
            atomicAdd(&acc[accIdx + 1], (double)(redw[4] + redw[5] + redw[6] + redw[7]));
        }
        return;
    }

    // ---- iir pass 1 ----
    const int tid   = (blk - NB_FFT) * 256 + threadIdx.x;   // NCHK*1024
    const int seq   = tid & (NSEQ - 1);
    const int chunk = tid >> 10;
    const int ch  = seq & 63;
    const int dir = (seq >> 6) & 1;
    const int b   = (seq >> 7) & 3;
    const int sg  = seq >> 9;
    const double a1 = cst[ch * 16 + 0], a2 = cst[ch * 16 + 1], b0 = cst[ch * 16 + 2];
    const float* x = (sg ? target : pred) + b * T_LEN;
    const int n0   = chunk * LC;
    const int base = dir ? (T_LEN - 1 - n0) : n0;
    const int stp  = dir ? -1 : 1;
    double y1 = 0.0, y2 = 0.0;
    #pragma unroll 4
    for (int i = 0; i < LC; ++i) {
        const double xv = (double)x[base + stp * i];
        const double y  = b0 * xv - a1 * y1 - a2 * y2;
        y2 = y1; y1 = y;
    }
    P[chunk * NSEQ + seq] = make_float2((float)y1, (float)y2);
}

// ---------- scan level A: group totals (affine offset of 16 chunks, zero init) ----------
__global__ __launch_bounds__(256) void iir_scanA(const double* __restrict__ cst,
                                                 const float2* __restrict__ P,
                                                 float2* __restrict__ Tg) {
    const int tid = blockIdx.x * 256 + threadIdx.x;     // NGRP*1024
    const int seq = tid & (NSEQ - 1);
    const int g   = tid >> 10;
    const int ch  = seq & 63;
    const double A00 = cst[ch * 16 + 3], A01 = cst[ch * 16 + 4];
    const double A10 = cst[ch * 16 + 5], A11 = cst[ch * 16 + 6];
    double t1 = 0.0, t2 = 0.0;
    #pragma unroll
    for (int j = 0; j < GRP; ++j) {
        const float2 p = P[(g * GRP + j) * NSEQ + seq];
        const double n1 = A00 * t1 + A01 * t2 + (double)p.x;
        const double n2 = A10 * t1 + A11 * t2 + (double)p.y;
        t1 = n1; t2 = n2;
    }
    Tg[g * NSEQ + seq] = make_float2((float)t1, (float)t2);
}

// ---------- pass 2: inline group-prefix (scanB) + chunk fixup + emit bf16 H ----------
// H layout: H[((sg*4+b)*16000 + tm)*128 + (dir*64+ch)]
__global__ __launch_bounds__(256) void iir_pass2(const float* __restrict__ pred,
                                                 const float* __restrict__ target,
                                                 const double* __restrict__ cst,
                                                 const float2* __restrict__ P,
                                                 const float2* __restrict__ Tg,
                                                 unsigned short* __restrict__ H) {
    const int tid = blockIdx.x * 256 + threadIdx.x;     // 160*1024
    const int seq = tid & (NSEQ - 1);
    const int c   = 160 + (tid >> 10);                  // chunks 160..319
    const int ch  = seq & 63;
    const int dir = (seq >> 6) & 1;
    const int b   = (seq >> 7) & 3;
    const int sg  = seq >> 9;
    const double a1 = cst[ch * 16 + 0], a2 = cst[ch * 16 + 1], b0 = cst[ch * 16 + 2];
    const double A00 = cst[ch * 16 + 3], A01 = cst[ch * 16 + 4];
    const double A10 = cst[ch * 16 + 5], A11 = cst[ch * 16 + 6];
    const double B00 = cst[ch * 16 + 7], B01 = cst[ch * 16 + 8];
    const double B10 = cst[ch * 16 + 9], B11 = cst[ch * 16 + 10];

    const int g = c >> 4;
    double y1 = 0.0, y2 = 0.0;
    for (int j = 0; j < g; ++j) {                       // group prefix (<=19 steps)
        const float2 t = Tg[j * NSEQ + seq];
        const double n1 = B00 * y1 + B01 * y2 + (double)t.x;
        const double n2 = B10 * y1 + B11 * y2 + (double)t.y;
        y1 = n1; y2 = n2;
    }
    for (int k = g * GRP; k < c; ++k) {                 // <=15 chunk fixups
        const float2 p = P[k * NSEQ + seq];
        const double n1 = A00 * y1 + A01 * y2 + (double)p.x;
        const double n2 = A10 * y1 + A11 * y2 + (double)p.y;
        y1 = n1; y2 = n2;
    }

    const float* x = (sg ? target : pred) + b * T_LEN;
    const int n0 = c * LC;
    unsigned short* Hb = H + (size_t)(sg * 4 + b) * 16000 * 128 + (dir * 64 + ch);
    if (dir == 0) {
        #pragma unroll 4
        for (int i = 0; i < LC; ++i) {
            const int n = n0 + i;
            const double xv = (double)x[n];
            const double y  = b0 * xv - a1 * y1 - a2 * y2;
            Hb[(size_t)(n - 16000) * 128] = f32_to_bf16((float)y);
            y2 = y1; y1 = y;
        }
    } else {
        #pragma unroll 4
        for (int i = 0; i < LC; ++i) {
            const int n = n0 + i;
            const double xv = (double)x[T_LEN - 1 - n];
            const double y  = b0 * xv - a1 * y1 - a2 * y2;
            Hb[(size_t)(31999 - n) * 128] = f32_to_bf16((float)y);
            y2 = y1; y1 = y;
        }
    }
}

// ---------- embedding GEMM (MFMA bf16) + tanh + |diff| reduction; l_raw folded in ----------
__global__ __launch_bounds__(256) void embed_kernel(const float* __restrict__ W,
                                                    const unsigned short* __restrict__ H,
                                                    const float* __restrict__ pred,
                                                    const float* __restrict__ target,
                                                    double* __restrict__ acc) {
    {   // l_raw: grid is exactly 250*256 = 64000 threads
        const int i  = blockIdx.x * 256 + threadIdx.x;
        const int bb = i / 16000;
        const int t  = i - bb * 16000 + 16000;
        float r = fabsf(pred[bb * T_LEN + t] - target[bb * T_LEN + t]);
        for (int off = 32; off >= 1; off >>= 1) r += __shfl_down(r, off, 64);
        if ((threadIdx.x & 63) == 0) atomicAdd(&acc[7], (double)r);
    }

    const int lane = threadIdx.x & 63;
    const int wave = threadIdx.x >> 6;
    const int gw   = blockIdx.x * 4 + wave;      // 0..999 = n-tile index
    const int row  = lane & 15;
    const int quad = lane >> 4;

    short8 A[4][4];
    #pragma unroll
    for (int mi = 0; mi < 4; ++mi)
        #pragma unroll
        for (int ki = 0; ki < 4; ++ki) {
            const float* wp = W + (mi * 16 + row) * 128 + ki * 32 + quad * 8;
            short8 a;
            #pragma unroll
            for (int j = 0; j < 8; ++j) a[j] = (short)f32_to_bf16(wp[j]);
            A[mi][ki] = a;
        }

    float lsum = 0.f;
    const int t0 = gw * 16;
    for (int b = 0; b < 4; ++b) {
        const unsigned short* hp = H + (size_t)(b * 16000 + t0 + row) * 128 + quad * 8;
        const unsigned short* ht = hp + (size_t)4 * 16000 * 128;
        f32x4 accp[4], acct[4];
        #pragma unroll
        for (int mi = 0; mi < 4; ++mi) {
            accp[mi] = f32x4{0.f, 0.f, 0.f, 0.f};
            acct[mi] = f32x4{0.f, 0.f, 0.f, 0.f};
        }
        #pragma unroll
        for (int ki = 0; ki < 4; ++ki) {
            const short8 bp = *(const short8*)(hp + ki * 32);
            const short8 bt = *(const short8*)(ht + ki * 32);
            #pragma unroll
            for (int mi = 0; mi < 4; ++mi) {
                accp[mi] = __builtin_amdgcn_mfma_f32_16x16x32_bf16(A[mi][ki], bp, accp[mi], 0, 0, 0);
                acct[mi] = __builtin_amdgcn_mfma_f32_16x16x32_bf16(A[mi][ki], bt, acct[mi], 0, 0, 0);
            }
        }
        #pragma unroll
        for (int mi = 0; mi < 4; ++mi)
            #pragma unroll
            for (int r = 0; r < 4; ++r) {
                const float ep = fast_tanh(accp[mi][r]);
                const float et = fast_tanh(acct[mi][r]);
                lsum += fabsf(ep - et);
            }
    }
    for (int off = 32; off >= 1; off >>= 1) lsum += __shfl_down(lsum, off, 64);
    if (lane == 0) atomicAdd(&acc[6], (double)lsum);
}

// ---------- finalize ----------
__global__ void finalize_kernel(const double* __restrict__ acc, float* __restrict__ out) {
    if (threadIdx.x == 0 && blockIdx.x == 0) {
        double lm = (acc[0] + acc[1]) / (4.0 * 372.0 * 257.0);
        lm       += (acc[2] + acc[3]) / (4.0 * 184.0 * 513.0);
        lm       += (acc[4] + acc[5]) / (4.0 * 90.0 * 1025.0);
        const double la = acc[6] / (4.0 * 64.0 * 16000.0);
        const double lr = acc[7] / 64000.0 * 0.1;
        out[0] = (float)(lm + 10.0 * la + lr);
        out[1] = (float)lm;
        out[2] = (float)la;
    }
}

extern "C" void kernel_launch(void* const* d_in, const int* in_sizes, int n_in,
                              void* d_out, int out_size, void* d_ws, size_t ws_size,
                              hipStream_t stream) {
    const float* pred   = (const float*)d_in[0];
    const float* target = (const float*)d_in[1];
    const float* W      = (const float*)d_in[2];
    float* out = (float*)d_out;

    // workspace layout (16B aligned), total ~35.6 MB
    char* ws = (char*)d_ws;
    double*  acc = (double*)ws;                               // 64 B
    double*  cst = (double*)(ws + 256);                       // 64*16*8 = 8192 B
    float2*  P   = (float2*)(ws + 16384);                     // 320*1024*8 = 2,621,440 B
    float2*  Tg  = (float2*)(ws + 2637824);                   // 20*1024*8 = 163,840 B
    unsigned short* H = (unsigned short*)(ws + 2965504);      // 8*16000*128*2 = 32,768,000 B

    hipLaunchKernelGGL(setup_kernel,  dim3(1), dim3(64), 0, stream, cst, acc);
    hipLaunchKernelGGL(phase1_kernel, dim3(NB_FFT + NB_P1), dim3(256), 0, stream, pred, target, cst, P, acc);
    hipLaunchKernelGGL(iir_scanA,     dim3(NGRP * 4), dim3(256), 0, stream, cst, P, Tg);
    hipLaunchKernelGGL(iir_pass2,     dim3(640), dim3(256), 0, stream, pred, target, cst, P, Tg, H);
    hipLaunchKernelGGL(embed_kernel,  dim3(250), dim3(256), 0, stream, W, H, pred, target, acc);
    hipLaunchKernelGGL(finalize_kernel, dim3(1), dim3(1), 0, stream, acc, out);
}

// Round 4
// 133.766 us; speedup vs baseline: 1.9724x; 1.4760x over previous
//
#include <hip/hip_runtime.h>

#define T_LEN 48000
#define NSEQ  1024
#define LC    100      // chunk length
#define NCHK  320      // chunks 0..319 cover samples [0,32000) in traversal order
#define GRP   16       // chunks per scan group
#define NGRP  20       // groups

#define NB_F2048 360
#define NB_F1024 736
#define NB_F512  1488
#define NB_FFT   2584
#define NB_P1    1280  // NCHK*1024/256
#define NB_EMB   250

using short8 = __attribute__((ext_vector_type(8))) short;
using f32x4  = __attribute__((ext_vector_type(4))) float;

// ---------- channel filter constants (match reference numpy math, f64) ----------
__device__ __forceinline__ void chan_params(int ch, double& a1, double& a2, double& b0) {
    const double lf = log(10.0) + (double)ch * (log(100.0) - log(10.0)) / 63.0;
    const double f  = exp(lf);
    const double r  = 0.9999 + (double)ch * (0.99999 - 0.9999) / 63.0;
    const double th = 2.0 * 3.14159265358979323846 * f / 24000.0;
    a1 = -2.0 * r * cos(th);
    a2 = r * r;
    b0 = (1.0 - r) * 0.5;
}

__device__ __forceinline__ unsigned short f32_to_bf16(float f) {
    unsigned u = __float_as_uint(f);
    u += 0x7fffu + ((u >> 16) & 1u);     // round-to-nearest-even
    return (unsigned short)(u >> 16);
}

__device__ __forceinline__ float fast_tanh(float x) {
    const float e = __expf(2.0f * x);
    return 1.0f - 2.0f / (e + 1.0f);
}

__device__ __forceinline__ float2 cmul(float2 a, float2 b) {
    return make_float2(a.x * b.x - a.y * b.y, a.x * b.y + a.y * b.x);
}
__device__ __forceinline__ float2 cadd(float2 a, float2 b) { return make_float2(a.x + b.x, a.y + b.y); }
__device__ __forceinline__ float2 csub(float2 a, float2 b) { return make_float2(a.x - b.x, a.y - b.y); }

// ---------- setup: per-channel constant table ----------
// cst[ch*16 + {0,1,2}] = a1,a2,b0 ; {3..6} = A = M^LC ; {7..10} = A16 = A^GRP
__global__ void setup_kernel(double* __restrict__ cst) {
    const int t = threadIdx.x;
    if (t < 64) {
        double a1, a2, b0; chan_params(t, a1, a2, b0);
        double m00 = -a1, m01 = -a2, m10 = 1.0, m11 = 0.0;
        double r00 = 1.0, r01 = 0.0, r10 = 0.0, r11 = 1.0;
        int e = LC;
        while (e) {
            if (e & 1) {
                const double t00 = r00 * m00 + r01 * m10, t01 = r00 * m01 + r01 * m11;
                const double t10 = r10 * m00 + r11 * m10, t11 = r10 * m01 + r11 * m11;
                r00 = t00; r01 = t01; r10 = t10; r11 = t11;
            }
            const double q00 = m00 * m00 + m01 * m10, q01 = m00 * m01 + m01 * m11;
            const double q10 = m10 * m00 + m11 * m10, q11 = m10 * m01 + m11 * m11;
            m00 = q00; m01 = q01; m10 = q10; m11 = q11;
            e >>= 1;
        }
        cst[t * 16 + 0] = a1; cst[t * 16 + 1] = a2; cst[t * 16 + 2] = b0;
        cst[t * 16 + 3] = r00; cst[t * 16 + 4] = r01;
        cst[t * 16 + 5] = r10; cst[t * 16 + 6] = r11;
        double q00 = r00, q01 = r01, q10 = r10, q11 = r11;
        #pragma unroll
        for (int s = 0; s < 4; ++s) {   // A^16 via 4 squarings
            const double n00 = q00 * q00 + q01 * q10, n01 = q00 * q01 + q01 * q11;
            const double n10 = q10 * q00 + q11 * q10, n11 = q10 * q01 + q11 * q11;
            q00 = n00; q01 = n01; q10 = n10; q11 = n11;
        }
        cst[t * 16 + 7] = q00; cst[t * 16 + 8]  = q01;
        cst[t * 16 + 9] = q10; cst[t * 16 + 10] = q11;
    }
}

// ---------- phase1: FFT/MSS blocks (heavy N first) + iir_pass1 blocks ----------
// NO atomics: each FFT block writes one pre-scaled double partial.
__global__ __launch_bounds__(256) void phase1_kernel(const float* __restrict__ pred,
                                                     const float* __restrict__ target,
                                                     const double* __restrict__ cst,
                                                     float2* __restrict__ P,
                                                     double* __restrict__ fftP) {
    __shared__ float2 bufA[2048];
    __shared__ float2 bufB[2048];
    __shared__ float2 twl[512];     // tw[k] = exp(-2*pi*i*k/N), k < N/4
    __shared__ float redw[8];
    const int blk = blockIdx.x;

    if (blk < NB_FFT) {
        int N, HOP, id;
        double scale;
        if (blk < NB_F2048)                  { N = 2048; HOP = 512; id = blk;
                                               scale = 1.0 / (4.0 * 90.0 * 1025.0); }
        else if (blk < NB_F2048 + NB_F1024)  { N = 1024; HOP = 256; id = blk - NB_F2048;
                                               scale = 1.0 / (4.0 * 184.0 * 513.0); }
        else                                 { N = 512;  HOP = 128; id = blk - NB_F2048 - NB_F1024;
                                               scale = 1.0 / (4.0 * 372.0 * 257.0); }
        const int tid = threadIdx.x;
        const int b   = id & 3;
        const int fr  = id >> 2;
        const int N4  = N >> 2;
        const float* xp = pred   + b * T_LEN + fr * HOP;
        const float* xt = target + b * T_LEN + fr * HOP;

        const float wstep = -6.283185307179586f / (float)N;
        for (int k = tid; k < N4; k += 256) {
            float sn, cs; __sincosf(wstep * (float)k, &sn, &cs);
            twl[k] = make_float2(cs, sn);
        }
        for (int i = tid; i < N; i += 256) bufA[i] = make_float2(xp[i], xt[i]);
        __syncthreads();

        float2* X = bufA; float2* Y = bufB;
        int s = 1, ls = 0;
        while ((s << 2) <= N) {                    // fused radix-4 stages
            for (int i = tid; i < N4; i += 256) {
                const int p  = i >> ls;
                const int q  = i & (s - 1);
                const int k1 = p << ls;            // s*p < N/4
                const float2 a0 = X[i];
                const float2 a1 = X[i + N4];
                const float2 a2 = X[i + 2 * N4];
                const float2 a3 = X[i + 3 * N4];
                const float2 w1 = twl[k1];
                const int   k2 = k1 << 1;          // 2*s*p < N/2
                const float2 t2 = twl[k2 & (N4 - 1)];
                const float2 w2 = (k2 < N4) ? t2 : make_float2(t2.y, -t2.x);
                const float2 e1 = cadd(a0, a2), d1 = csub(a0, a2);
                const float2 e2 = cadd(a1, a3), d2 = csub(a1, a3);
                const float2 o1 = cmul(d1, w1);
                const float2 ot = cmul(d2, w1);
                const float2 o2 = make_float2(ot.y, -ot.x);      // * (-i)
                const float2 E1 = cadd(e1, e2);
                const float2 O1 = cmul(csub(e1, e2), w2);
                const float2 E2 = cadd(o1, o2);
                const float2 O2 = cmul(csub(o1, o2), w2);
                const int o4 = q + (p << (ls + 2));               // q + 4*s*p
                Y[o4]         = E1;
                Y[o4 + s]     = E2;
                Y[o4 + 2 * s] = O1;
                Y[o4 + 3 * s] = O2;
            }
            __syncthreads();
            float2* t = X; X = Y; Y = t;
            s <<= 2; ls += 2;
        }
        // If s == N/2 one radix-2 stage (tw=1) remains: fold it into the epilogue.
        const bool rad2 = (s < N);
        const int  half = N >> 1;

        float s1 = 0.f, s2 = 0.f;
        for (int k = tid; k <= half; k += 256) {
            const int k2 = (N - k) & (N - 1);
            float2 zk, zn;
            if (rad2) {
                zk = (k  < half) ? cadd(X[k],  X[k  + half]) : csub(X[k  - half], X[k]);
                zn = (k2 < half) ? cadd(X[k2], X[k2 + half]) : csub(X[k2 - half], X[k2]);
            } else {
                zk = X[k]; zn = X[k2];
            }
            const float xpr = 0.5f * (zk.x + zn.x), xpi = 0.5f * (zk.y - zn.y);
            const float xtr = 0.5f * (zk.y + zn.y), xti = 0.5f * (zn.x - zk.x);
            const float xm = sqrtf(xpr * xpr + xpi * xpi) + 1e-7f;
            const float ym = sqrtf(xtr * xtr + xti * xti) + 1e-7f;
            s1 += fabsf(xm - ym);
            s2 += fabsf(__logf(xm) - __logf(ym));
        }
        for (int off = 32; off >= 1; off >>= 1) {
            s1 += __shfl_down(s1, off, 64);
            s2 += __shfl_down(s2, off, 64);
        }
        const int lane = tid & 63, wv = tid >> 6;
        if (lane == 0) { redw[wv] = s1; redw[wv + 4] = s2; }
        __syncthreads();
        if (tid == 0) {
            const double t1 = (double)redw[0] + (double)redw[1] + (double)redw[2] + (double)redw[3];
            const double t2 = (double)redw[4] + (double)redw[5] + (double)redw[6] + (double)redw[7];
            fftP[blk] = (t1 + t2) * scale;      // plain store, no contention
        }
        return;
    }

    // ---- iir pass 1 ----
    const int tid   = (blk - NB_FFT) * 256 + threadIdx.x;   // NCHK*1024
    const int seq   = tid & (NSEQ - 1);
    const int chunk = tid >> 10;
    const int ch  = seq & 63;
    const int dir = (seq >> 6) & 1;
    const int b   = (seq >> 7) & 3;
    const int sg  = seq >> 9;
    const double a1 = cst[ch * 16 + 0], a2 = cst[ch * 16 + 1], b0 = cst[ch * 16 + 2];
    const float* x = (sg ? target : pred) + b * T_LEN;
    const int n0   = chunk * LC;
    const int base = dir ? (T_LEN - 1 - n0) : n0;
    const int stp  = dir ? -1 : 1;
    double y1 = 0.0, y2 = 0.0;
    #pragma unroll 4
    for (int i = 0; i < LC; ++i) {
        const double xv = (double)x[base + stp * i];
        const double y  = b0 * xv - a1 * y1 - a2 * y2;
        y2 = y1; y1 = y;
    }
    P[chunk * NSEQ + seq] = make_float2((float)y1, (float)y2);
}

// ---------- scan level A: group totals (affine offset of 16 chunks, zero init) ----------
__global__ __launch_bounds__(256) void iir_scanA(const double* __restrict__ cst,
                                                 const float2* __restrict__ P,
                                                 float2* __restrict__ Tg) {
    const int tid = blockIdx.x * 256 + threadIdx.x;     // NGRP*1024
    const int seq = tid & (NSEQ - 1);
    const int g   = tid >> 10;
    const int ch  = seq & 63;
    const double A00 = cst[ch * 16 + 3], A01 = cst[ch * 16 + 4];
    const double A10 = cst[ch * 16 + 5], A11 = cst[ch * 16 + 6];
    double t1 = 0.0, t2 = 0.0;
    #pragma unroll
    for (int j = 0; j < GRP; ++j) {
        const float2 p = P[(g * GRP + j) * NSEQ + seq];
        const double n1 = A00 * t1 + A01 * t2 + (double)p.x;
        const double n2 = A10 * t1 + A11 * t2 + (double)p.y;
        t1 = n1; t2 = n2;
    }
    Tg[g * NSEQ + seq] = make_float2((float)t1, (float)t2);
}

// ---------- pass 2: inline group-prefix + chunk fixup + emit bf16 H ----------
// H layout: H[((sg*4+b)*16000 + tm)*128 + (dir*64+ch)]
__global__ __launch_bounds__(256) void iir_pass2(const float* __restrict__ pred,
                                                 const float* __restrict__ target,
                                                 const double* __restrict__ cst,
                                                 const float2* __restrict__ P,
                                                 const float2* __restrict__ Tg,
                                                 unsigned short* __restrict__ H) {
    const int tid = blockIdx.x * 256 + threadIdx.x;     // 160*1024
    const int seq = tid & (NSEQ - 1);
    const int c   = 160 + (tid >> 10);                  // chunks 160..319
    const int ch  = seq & 63;
    const int dir = (seq >> 6) & 1;
    const int b   = (seq >> 7) & 3;
    const int sg  = seq >> 9;
    const double a1 = cst[ch * 16 + 0], a2 = cst[ch * 16 + 1], b0 = cst[ch * 16 + 2];
    const double A00 = cst[ch * 16 + 3], A01 = cst[ch * 16 + 4];
    const double A10 = cst[ch * 16 + 5], A11 = cst[ch * 16 + 6];
    const double B00 = cst[ch * 16 + 7], B01 = cst[ch * 16 + 8];
    const double B10 = cst[ch * 16 + 9], B11 = cst[ch * 16 + 10];

    const int g = c >> 4;
    double y1 = 0.0, y2 = 0.0;
    for (int j = 0; j < g; ++j) {                       // group prefix (<=19 steps)
        const float2 t = Tg[j * NSEQ + seq];
        const double n1 = B00 * y1 + B01 * y2 + (double)t.x;
        const double n2 = B10 * y1 + B11 * y2 + (double)t.y;
        y1 = n1; y2 = n2;
    }
    for (int k = g * GRP; k < c; ++k) {                 // <=15 chunk fixups
        const float2 p = P[k * NSEQ + seq];
        const double n1 = A00 * y1 + A01 * y2 + (double)p.x;
        const double n2 = A10 * y1 + A11 * y2 + (double)p.y;
        y1 = n1; y2 = n2;
    }

    const float* x = (sg ? target : pred) + b * T_LEN;
    const int n0 = c * LC;
    unsigned short* Hb = H + (size_t)(sg * 4 + b) * 16000 * 128 + (dir * 64 + ch);
    if (dir == 0) {
        #pragma unroll 4
        for (int i = 0; i < LC; ++i) {
            const int n = n0 + i;
            const double xv = (double)x[n];
            const double y  = b0 * xv - a1 * y1 - a2 * y2;
            Hb[(size_t)(n - 16000) * 128] = f32_to_bf16((float)y);
            y2 = y1; y1 = y;
        }
    } else {
        #pragma unroll 4
        for (int i = 0; i < LC; ++i) {
            const int n = n0 + i;
            const double xv = (double)x[T_LEN - 1 - n];
            const double y  = b0 * xv - a1 * y1 - a2 * y2;
            Hb[(size_t)(31999 - n) * 128] = f32_to_bf16((float)y);
            y2 = y1; y1 = y;
        }
    }
}

// ---------- embedding GEMM (MFMA bf16) + tanh + |diff|; l_raw folded; no atomics ----------
__global__ __launch_bounds__(256) void embed_kernel(const float* __restrict__ W,
                                                    const unsigned short* __restrict__ H,
                                                    const float* __restrict__ pred,
                                                    const float* __restrict__ target,
                                                    double2* __restrict__ emP) {
    __shared__ double em[8];
    float rsum;
    {   // l_raw: grid is exactly 250*256 = 64000 threads
        const int i  = blockIdx.x * 256 + threadIdx.x;
        const int bb = i / 16000;
        const int t  = i - bb * 16000 + 16000;
        rsum = fabsf(pred[bb * T_LEN + t] - target[bb * T_LEN + t]);
        for (int off = 32; off >= 1; off >>= 1) rsum += __shfl_down(rsum, off, 64);
    }

    const int lane = threadIdx.x & 63;
    const int wave = threadIdx.x >> 6;
    const int gw   = blockIdx.x * 4 + wave;      // 0..999 = n-tile index
    const int row  = lane & 15;
    const int quad = lane >> 4;

    short8 A[4][4];
    #pragma unroll
    for (int mi = 0; mi < 4; ++mi)
        #pragma unroll
        for (int ki = 0; ki < 4; ++ki) {
            const float* wp = W + (mi * 16 + row) * 128 + ki * 32 + quad * 8;
            short8 a;
            #pragma unroll
            for (int j = 0; j < 8; ++j) a[j] = (short)f32_to_bf16(wp[j]);
            A[mi][ki] = a;
        }

    float lsum = 0.f;
    const int t0 = gw * 16;
    for (int b = 0; b < 4; ++b) {
        const unsigned short* hp = H + (size_t)(b * 16000 + t0 + row) * 128 + quad * 8;
        const unsigned short* ht = hp + (size_t)4 * 16000 * 128;
        f32x4 accp[4], acct[4];
        #pragma unroll
        for (int mi = 0; mi < 4; ++mi) {
            accp[mi] = f32x4{0.f, 0.f, 0.f, 0.f};
            acct[mi] = f32x4{0.f, 0.f, 0.f, 0.f};
        }
        #pragma unroll
        for (int ki = 0; ki < 4; ++ki) {
            const short8 bp = *(const short8*)(hp + ki * 32);
            const short8 bt = *(const short8*)(ht + ki * 32);
            #pragma unroll
            for (int mi = 0; mi < 4; ++mi) {
                accp[mi] = __builtin_amdgcn_mfma_f32_16x16x32_bf16(A[mi][ki], bp, accp[mi], 0, 0, 0);
                acct[mi] = __builtin_amdgcn_mfma_f32_16x16x32_bf16(A[mi][ki], bt, acct[mi], 0, 0, 0);
            }
        }
        #pragma unroll
        for (int mi = 0; mi < 4; ++mi)
            #pragma unroll
            for (int r = 0; r < 4; ++r) {
                const float ep = fast_tanh(accp[mi][r]);
                const float et = fast_tanh(acct[mi][r]);
                lsum += fabsf(ep - et);
            }
    }
    for (int off = 32; off >= 1; off >>= 1) lsum += __shfl_down(lsum, off, 64);
    if (lane == 0) { em[wave] = (double)lsum; em[wave + 4] = (double)rsum; }
    __syncthreads();
    if (threadIdx.x == 0)
        emP[blockIdx.x] = make_double2(em[0] + em[1] + em[2] + em[3],
                                       em[4] + em[5] + em[6] + em[7]);
}

// ---------- finalize: reduce partials ----------
__global__ __launch_bounds__(256) void finalize_kernel(const double* __restrict__ fftP,
                                                       const double2* __restrict__ emP,
                                                       float* __restrict__ out) {
    __shared__ double red[256];
    const int tid = threadIdx.x;
    double lm = 0.0;
    for (int i = tid; i < NB_FFT; i += 256) lm += fftP[i];
    double la = 0.0, lr = 0.0;
    for (int i = tid; i < NB_EMB; i += 256) { const double2 e = emP[i]; la += e.x; lr += e.y; }

    red[tid] = lm; __syncthreads();
    for (int o = 128; o > 0; o >>= 1) { if (tid < o) red[tid] += red[tid + o]; __syncthreads(); }
    lm = red[0]; __syncthreads();
    red[tid] = la; __syncthreads();
    for (int o = 128; o > 0; o >>= 1) { if (tid < o) red[tid] += red[tid + o]; __syncthreads(); }
    la = red[0]; __syncthreads();
    red[tid] = lr; __syncthreads();
    for (int o = 128; o > 0; o >>= 1) { if (tid < o) red[tid] += red[tid + o]; __syncthreads(); }
    if (tid == 0) {
        lr = red[0] / 64000.0 * 0.1;
        la = la / (4.0 * 64.0 * 16000.0);
        out[0] = (float)(lm + 10.0 * la + lr);
        out[1] = (float)lm;
        out[2] = (float)la;
    }
}

extern "C" void kernel_launch(void* const* d_in, const int* in_sizes, int n_in,
                              void* d_out, int out_size, void* d_ws, size_t ws_size,
                              hipStream_t stream) {
    const float* pred   = (const float*)d_in[0];
    const float* target = (const float*)d_in[1];
    const float* W      = (const float*)d_in[2];
    float* out = (float*)d_out;

    // workspace layout, total ~35.6 MB
    char* ws = (char*)d_ws;
    double*  cst  = (double*)ws;                              // 8192 B
    double*  fftP = (double*)(ws + 8192);                     // 2584*8 = 20672 B
    double2* emP  = (double2*)(ws + 28928);                   // 250*16 = 4000 B
    float2*  P    = (float2*)(ws + 33280);                    // 320*1024*8 = 2,621,440 B
    float2*  Tg   = (float2*)(ws + 2654720);                  // 20*1024*8 = 163,840 B
    unsigned short* H = (unsigned short*)(ws + 2818560);      // 8*16000*128*2 = 32,768,000 B

    hipLaunchKernelGGL(setup_kernel,  dim3(1), dim3(64), 0, stream, cst);
    hipLaunchKernelGGL(phase1_kernel, dim3(NB_FFT + NB_P1), dim3(256), 0, stream, pred, target, cst, P, fftP);
    hipLaunchKernelGGL(iir_scanA,     dim3(NGRP * 4), dim3(256), 0, stream, cst, P, Tg);
    hipLaunchKernelGGL(iir_pass2,     dim3(640), dim3(256), 0, stream, pred, target, cst, P, Tg, H);
    hipLaunchKernelGGL(embed_kernel,  dim3(NB_EMB), dim3(256), 0, stream, W, H, pred, target, emP);
    hipLaunchKernelGGL(finalize_kernel, dim3(1), dim3(256), 0, stream, fftP, emP, out);
}

// Round 5
// 126.372 us; speedup vs baseline: 2.0879x; 1.0585x over previous
//
#include <hip/hip_runtime.h>

#define T_LEN 48000
#define NSEQ  1024
#define LC    100      // chunk length
#define NCHK  320      // chunks 0..319 cover samples [0,32000) in traversal order
#define GRP   16       // chunks per scan group
#define NGRP  20       // groups

#define NB_F2048 360
#define NB_F1024 736
#define NB_F512  744   // 1488 frames, 2 per block
#define NB_FFT   1840
#define NB_P1    1280  // NCHK*1024/256
#define NB_EMB   250
#define NFRAMES  2584

using short8 = __attribute__((ext_vector_type(8))) short;
using f32x4  = __attribute__((ext_vector_type(4))) float;

// ---------- channel filter constants (match reference numpy math, f64) ----------
__device__ __forceinline__ void chan_params(int ch, double& a1, double& a2, double& b0) {
    const double lf = log(10.0) + (double)ch * (log(100.0) - log(10.0)) / 63.0;
    const double f  = exp(lf);
    const double r  = 0.9999 + (double)ch * (0.99999 - 0.9999) / 63.0;
    const double th = 2.0 * 3.14159265358979323846 * f / 24000.0;
    a1 = -2.0 * r * cos(th);
    a2 = r * r;
    b0 = (1.0 - r) * 0.5;
}

__device__ __forceinline__ unsigned short f32_to_bf16(float f) {
    unsigned u = __float_as_uint(f);
    u += 0x7fffu + ((u >> 16) & 1u);     // round-to-nearest-even
    return (unsigned short)(u >> 16);
}

__device__ __forceinline__ float fast_tanh(float x) {
    const float e = __expf(2.0f * x);
    return 1.0f - 2.0f / (e + 1.0f);
}

__device__ __forceinline__ float2 cmul(float2 a, float2 b) {
    return make_float2(a.x * b.x - a.y * b.y, a.x * b.y + a.y * b.x);
}
__device__ __forceinline__ float2 cadd(float2 a, float2 b) { return make_float2(a.x + b.x, a.y + b.y); }
__device__ __forceinline__ float2 csub(float2 a, float2 b) { return make_float2(a.x - b.x, a.y - b.y); }

// ---------- setup: per-channel constant table ----------
// cst[ch*16 + {0,1,2}] = a1,a2,b0 ; {3..6} = A = M^LC ; {7..10} = A16 = A^GRP
__global__ void setup_kernel(double* __restrict__ cst) {
    const int t = threadIdx.x;
    if (t < 64) {
        double a1, a2, b0; chan_params(t, a1, a2, b0);
        double m00 = -a1, m01 = -a2, m10 = 1.0, m11 = 0.0;
        double r00 = 1.0, r01 = 0.0, r10 = 0.0, r11 = 1.0;
        int e = LC;
        while (e) {
            if (e & 1) {
                const double t00 = r00 * m00 + r01 * m10, t01 = r00 * m01 + r01 * m11;
                const double t10 = r10 * m00 + r11 * m10, t11 = r10 * m01 + r11 * m11;
                r00 = t00; r01 = t01; r10 = t10; r11 = t11;
            }
            const double q00 = m00 * m00 + m01 * m10, q01 = m00 * m01 + m01 * m11;
            const double q10 = m10 * m00 + m11 * m10, q11 = m10 * m01 + m11 * m11;
            m00 = q00; m01 = q01; m10 = q10; m11 = q11;
            e >>= 1;
        }
        cst[t * 16 + 0] = a1; cst[t * 16 + 1] = a2; cst[t * 16 + 2] = b0;
        cst[t * 16 + 3] = r00; cst[t * 16 + 4] = r01;
        cst[t * 16 + 5] = r10; cst[t * 16 + 6] = r11;
        double q00 = r00, q01 = r01, q10 = r10, q11 = r11;
        #pragma unroll
        for (int s = 0; s < 4; ++s) {   // A^16 via 4 squarings
            const double n00 = q00 * q00 + q01 * q10, n01 = q00 * q01 + q01 * q11;
            const double n10 = q10 * q00 + q11 * q10, n11 = q10 * q01 + q11 * q11;
            q00 = n00; q01 = n01; q10 = n10; q11 = n11;
        }
        cst[t * 16 + 7] = q00; cst[t * 16 + 8]  = q01;
        cst[t * 16 + 9] = q10; cst[t * 16 + 10] = q11;
    }
}

// ---------- phase1: FFT/MSS blocks (heavy N first, 2x512-frames packed) + iir_pass1 ----------
__global__ __launch_bounds__(256) void phase1_kernel(const float* __restrict__ pred,
                                                     const float* __restrict__ target,
                                                     const double* __restrict__ cst,
                                                     float2* __restrict__ P,
                                                     double* __restrict__ fftP) {
    __shared__ float2 bufA[2048];
    __shared__ float2 bufB[2048];
    __shared__ float2 twl[512];     // tw[k] = exp(-2*pi*i*k/N), k < N/4
    __shared__ float redw[4];
    const int blk = blockIdx.x;

    if (blk < NB_FFT) {
        // packed: for N=512 two frames per block (threads split 128/128)
        int N, HOP, frame0, nthr, lt, off;
        double scale;
        const int tid = threadIdx.x;
        if (blk < NB_F2048) {
            N = 2048; HOP = 512; scale = 1.0 / (4.0 * 90.0 * 1025.0);
            frame0 = blk; nthr = 256; lt = tid; off = 0;
        } else if (blk < NB_F2048 + NB_F1024) {
            N = 1024; HOP = 256; scale = 1.0 / (4.0 * 184.0 * 513.0);
            frame0 = blk; nthr = 256; lt = tid; off = 0;
        } else {
            N = 512;  HOP = 128; scale = 1.0 / (4.0 * 372.0 * 257.0);
            const int id = blk - (NB_F2048 + NB_F1024);
            frame0 = NB_F2048 + NB_F1024 + 2 * id + (tid >> 7);
            nthr = 128; lt = tid & 127; off = (tid >> 7) << 9;    // 0 or 512
        }
        // frame -> (b, fr) within its config
        int fidL;   // frame index local to config
        if (blk < NB_F2048) fidL = frame0;
        else if (blk < NB_F2048 + NB_F1024) fidL = frame0 - NB_F2048;
        else fidL = frame0 - (NB_F2048 + NB_F1024);
        const int b  = fidL & 3;
        const int fr = fidL >> 2;
        const int N4 = N >> 2;
        const float* xp = pred   + b * T_LEN + fr * HOP;
        const float* xt = target + b * T_LEN + fr * HOP;

        const float wstep = -6.283185307179586f / (float)N;
        for (int k = tid; k < N4; k += 256) {    // shared by both packed halves (same N)
            float sn, cs; __sincosf(wstep * (float)k, &sn, &cs);
            twl[k] = make_float2(cs, sn);
        }
        for (int i = lt; i < N; i += nthr) bufA[off + i] = make_float2(xp[i], xt[i]);
        __syncthreads();

        float2* X = bufA; float2* Y = bufB;
        int s = 1, ls = 0;
        while ((s << 2) <= N) {                    // fused radix-4 stages
            for (int i = lt; i < N4; i += nthr) {
                const int p  = i >> ls;
                const int q  = i & (s - 1);
                const int k1 = p << ls;            // s*p < N/4
                const float2 a0 = X[off + i];
                const float2 a1 = X[off + i + N4];
                const float2 a2 = X[off + i + 2 * N4];
                const float2 a3 = X[off + i + 3 * N4];
                const float2 w1 = twl[k1];
                const int   k2 = k1 << 1;          // 2*s*p < N/2
                const float2 t2 = twl[k2 & (N4 - 1)];
                const float2 w2 = (k2 < N4) ? t2 : make_float2(t2.y, -t2.x);
                const float2 e1 = cadd(a0, a2), d1 = csub(a0, a2);
                const float2 e2 = cadd(a1, a3), d2 = csub(a1, a3);
                const float2 o1 = cmul(d1, w1);
                const float2 ot = cmul(d2, w1);
                const float2 o2 = make_float2(ot.y, -ot.x);      // * (-i)
                const float2 E1 = cadd(e1, e2);
                const float2 O1 = cmul(csub(e1, e2), w2);
                const float2 E2 = cadd(o1, o2);
                const float2 O2 = cmul(csub(o1, o2), w2);
                const int o4 = q + (p << (ls + 2));               // q + 4*s*p
                Y[off + o4]         = E1;
                Y[off + o4 + s]     = E2;
                Y[off + o4 + 2 * s] = O1;
                Y[off + o4 + 3 * s] = O2;
            }
            __syncthreads();
            float2* t = X; X = Y; Y = t;
            s <<= 2; ls += 2;
        }
        // If s == N/2 one radix-2 stage (tw=1) remains: fold into the epilogue.
        const bool rad2 = (s < N);
        const int  half = N >> 1;

        float ss = 0.f;
        for (int k = lt; k <= half; k += nthr) {
            const int k2 = (N - k) & (N - 1);
            float2 zk, zn;
            if (rad2) {
                zk = (k  < half) ? cadd(X[off + k],  X[off + k  + half]) : csub(X[off + k  - half], X[off + k]);
                zn = (k2 < half) ? cadd(X[off + k2], X[off + k2 + half]) : csub(X[off + k2 - half], X[off + k2]);
            } else {
                zk = X[off + k]; zn = X[off + k2];
            }
            const float xpr = 0.5f * (zk.x + zn.x), xpi = 0.5f * (zk.y - zn.y);
            const float xtr = 0.5f * (zk.y + zn.y), xti = 0.5f * (zn.x - zk.x);
            const float xm = sqrtf(xpr * xpr + xpi * xpi) + 1e-7f;
            const float ym = sqrtf(xtr * xtr + xti * xti) + 1e-7f;
            ss += fabsf(xm - ym) + fabsf(__logf(xm) - __logf(ym));
        }
        for (int o = 32; o >= 1; o >>= 1) ss += __shfl_down(ss, o, 64);
        const int lane = tid & 63, wv = tid >> 6;
        if (lane == 0) redw[wv] = ss;
        __syncthreads();
        if (nthr == 256) {
            if (tid == 0)
                fftP[frame0] = ((double)redw[0] + (double)redw[1] +
                                (double)redw[2] + (double)redw[3]) * scale;
        } else {
            if (lt == 0)   // tid 0 (waves 0,1) and tid 128 (waves 2,3)
                fftP[frame0] = ((double)redw[(tid >> 7) * 2] +
                                (double)redw[(tid >> 7) * 2 + 1]) * scale;
        }
        return;
    }

    // ---- iir pass 1 (f32 inner recurrence) ----
    const int tid   = (blk - NB_FFT) * 256 + threadIdx.x;   // NCHK*1024
    const int seq   = tid & (NSEQ - 1);
    const int chunk = tid >> 10;
    const int ch  = seq & 63;
    const int dir = (seq >> 6) & 1;
    const int b   = (seq >> 7) & 3;
    const int sg  = seq >> 9;
    const float a1f = (float)cst[ch * 16 + 0];
    const float a2f = (float)cst[ch * 16 + 1];
    const float b0f = (float)cst[ch * 16 + 2];
    const float* x = (sg ? target : pred) + b * T_LEN;
    const int n0   = chunk * LC;
    const int base = dir ? (T_LEN - 1 - n0) : n0;
    const int stp  = dir ? -1 : 1;
    float y1 = 0.f, y2 = 0.f;
    #pragma unroll 4
    for (int i = 0; i < LC; ++i) {
        const float xv = x[base + stp * i];
        const float y  = b0f * xv - a1f * y1 - a2f * y2;
        y2 = y1; y1 = y;
    }
    P[chunk * NSEQ + seq] = make_float2(y1, y2);
}

// ---------- scan level A: group totals (affine offset of 16 chunks, zero init) ----------
__global__ __launch_bounds__(256) void iir_scanA(const double* __restrict__ cst,
                                                 const float2* __restrict__ P,
                                                 float2* __restrict__ Tg) {
    const int tid = blockIdx.x * 256 + threadIdx.x;     // NGRP*1024
    const int seq = tid & (NSEQ - 1);
    const int g   = tid >> 10;
    const int ch  = seq & 63;
    const double A00 = cst[ch * 16 + 3], A01 = cst[ch * 16 + 4];
    const double A10 = cst[ch * 16 + 5], A11 = cst[ch * 16 + 6];
    double t1 = 0.0, t2 = 0.0;
    #pragma unroll
    for (int j = 0; j < GRP; ++j) {
        const float2 p = P[(g * GRP + j) * NSEQ + seq];
        const double n1 = A00 * t1 + A01 * t2 + (double)p.x;
        const double n2 = A10 * t1 + A11 * t2 + (double)p.y;
        t1 = n1; t2 = n2;
    }
    Tg[g * NSEQ + seq] = make_float2((float)t1, (float)t2);
}

// ---------- pass 2: inline group-prefix + chunk fixup (f64) + f32 recurrence, emit bf16 H ----------
// H layout: H[((sg*4+b)*16000 + tm)*128 + (dir*64+ch)]
__global__ __launch_bounds__(256) void iir_pass2(const float* __restrict__ pred,
                                                 const float* __restrict__ target,
                                                 const double* __restrict__ cst,
                                                 const float2* __restrict__ P,
                                                 const float2* __restrict__ Tg,
                                                 unsigned short* __restrict__ H) {
    const int tid = blockIdx.x * 256 + threadIdx.x;     // 160*1024
    const int seq = tid & (NSEQ - 1);
    const int c   = 160 + (tid >> 10);                  // chunks 160..319
    const int ch  = seq & 63;
    const int dir = (seq >> 6) & 1;
    const int b   = (seq >> 7) & 3;
    const int sg  = seq >> 9;
    const double A00 = cst[ch * 16 + 3], A01 = cst[ch * 16 + 4];
    const double A10 = cst[ch * 16 + 5], A11 = cst[ch * 16 + 6];
    const double B00 = cst[ch * 16 + 7], B01 = cst[ch * 16 + 8];
    const double B10 = cst[ch * 16 + 9], B11 = cst[ch * 16 + 10];

    const int g = c >> 4;
    double y1 = 0.0, y2 = 0.0;
    for (int j = 0; j < g; ++j) {                       // group prefix (<=19 steps)
        const float2 t = Tg[j * NSEQ + seq];
        const double n1 = B00 * y1 + B01 * y2 + (double)t.x;
        const double n2 = B10 * y1 + B11 * y2 + (double)t.y;
        y1 = n1; y2 = n2;
    }
    for (int k = g * GRP; k < c; ++k) {                 // <=15 chunk fixups
        const float2 p = P[k * NSEQ + seq];
        const double n1 = A00 * y1 + A01 * y2 + (double)p.x;
        const double n2 = A10 * y1 + A11 * y2 + (double)p.y;
        y1 = n1; y2 = n2;
    }

    const float a1f = (float)cst[ch * 16 + 0];
    const float a2f = (float)cst[ch * 16 + 1];
    const float b0f = (float)cst[ch * 16 + 2];
    float y1f = (float)y1, y2f = (float)y2;
    const float* x = (sg ? target : pred) + b * T_LEN;
    const int n0 = c * LC;
    unsigned short* Hb = H + (size_t)(sg * 4 + b) * 16000 * 128 + (dir * 64 + ch);
    if (dir == 0) {
        #pragma unroll 4
        for (int i = 0; i < LC; ++i) {
            const int n = n0 + i;
            const float xv = x[n];
            const float y  = b0f * xv - a1f * y1f - a2f * y2f;
            Hb[(size_t)(n - 16000) * 128] = f32_to_bf16(y);
            y2f = y1f; y1f = y;
        }
    } else {
        #pragma unroll 4
        for (int i = 0; i < LC; ++i) {
            const int n = n0 + i;
            const float xv = x[T_LEN - 1 - n];
            const float y  = b0f * xv - a1f * y1f - a2f * y2f;
            Hb[(size_t)(31999 - n) * 128] = f32_to_bf16(y);
            y2f = y1f; y1f = y;
        }
    }
}

// ---------- embedding GEMM (MFMA bf16) + tanh + |diff|; l_raw folded; no atomics ----------
__global__ __launch_bounds__(256) void embed_kernel(const float* __restrict__ W,
                                                    const unsigned short* __restrict__ H,
                                                    const float* __restrict__ pred,
                                                    const float* __restrict__ target,
                                                    double2* __restrict__ emP) {
    __shared__ double em[8];
    float rsum;
    {   // l_raw: grid is exactly 250*256 = 64000 threads
        const int i  = blockIdx.x * 256 + threadIdx.x;
        const int bb = i / 16000;
        const int t  = i - bb * 16000 + 16000;
        rsum = fabsf(pred[bb * T_LEN + t] - target[bb * T_LEN + t]);
        for (int off = 32; off >= 1; off >>= 1) rsum += __shfl_down(rsum, off, 64);
    }

    const int lane = threadIdx.x & 63;
    const int wave = threadIdx.x >> 6;
    const int gw   = blockIdx.x * 4 + wave;      // 0..999 = n-tile index
    const int row  = lane & 15;
    const int quad = lane >> 4;

    short8 A[4][4];
    #pragma unroll
    for (int mi = 0; mi < 4; ++mi)
        #pragma unroll
        for (int ki = 0; ki < 4; ++ki) {
            const float* wp = W + (mi * 16 + row) * 128 + ki * 32 + quad * 8;
            short8 a;
            #pragma unroll
            for (int j = 0; j < 8; ++j) a[j] = (short)f32_to_bf16(wp[j]);
            A[mi][ki] = a;
        }

    float lsum = 0.f;
    const int t0 = gw * 16;
    for (int b = 0; b < 4; ++b) {
        const unsigned short* hp = H + (size_t)(b * 16000 + t0 + row) * 128 + quad * 8;
        const unsigned short* ht = hp + (size_t)4 * 16000 * 128;
        f32x4 accp[4], acct[4];
        #pragma unroll
        for (int mi = 0; mi < 4; ++mi) {
            accp[mi] = f32x4{0.f, 0.f, 0.f, 0.f};
            acct[mi] = f32x4{0.f, 0.f, 0.f, 0.f};
        }
        #pragma unroll
        for (int ki = 0; ki < 4; ++ki) {
            const short8 bp = *(const short8*)(hp + ki * 32);
            const short8 bt = *(const short8*)(ht + ki * 32);
            #pragma unroll
            for (int mi = 0; mi < 4; ++mi) {
                accp[mi] = __builtin_amdgcn_mfma_f32_16x16x32_bf16(A[mi][ki], bp, accp[mi], 0, 0, 0);
                acct[mi] = __builtin_amdgcn_mfma_f32_16x16x32_bf16(A[mi][ki], bt, acct[mi], 0, 0, 0);
            }
        }
        #pragma unroll
        for (int mi = 0; mi < 4; ++mi)
            #pragma unroll
            for (int r = 0; r < 4; ++r) {
                const float ep = fast_tanh(accp[mi][r]);
                const float et = fast_tanh(acct[mi][r]);
                lsum += fabsf(ep - et);
            }
    }
    for (int off = 32; off >= 1; off >>= 1) lsum += __shfl_down(lsum, off, 64);
    if (lane == 0) { em[wave] = (double)lsum; em[wave + 4] = (double)rsum; }
    __syncthreads();
    if (threadIdx.x == 0)
        emP[blockIdx.x] = make_double2(em[0] + em[1] + em[2] + em[3],
                                       em[4] + em[5] + em[6] + em[7]);
}

// ---------- finalize: reduce partials ----------
__global__ __launch_bounds__(256) void finalize_kernel(const double* __restrict__ fftP,
                                                       const double2* __restrict__ emP,
                                                       float* __restrict__ out) {
    __shared__ double red[256];
    const int tid = threadIdx.x;
    double lm = 0.0;
    for (int i = tid; i < NFRAMES; i += 256) lm += fftP[i];
    double la = 0.0, lr = 0.0;
    for (int i = tid; i < NB_EMB; i += 256) { const double2 e = emP[i]; la += e.x; lr += e.y; }

    red[tid] = lm; __syncthreads();
    for (int o = 128; o > 0; o >>= 1) { if (tid < o) red[tid] += red[tid + o]; __syncthreads(); }
    lm = red[0]; __syncthreads();
    red[tid] = la; __syncthreads();
    for (int o = 128; o > 0; o >>= 1) { if (tid < o) red[tid] += red[tid + o]; __syncthreads(); }
    la = red[0]; __syncthreads();
    red[tid] = lr; __syncthreads();
    for (int o = 128; o > 0; o >>= 1) { if (tid < o) red[tid] += red[tid + o]; __syncthreads(); }
    if (tid == 0) {
        lr = red[0] / 64000.0 * 0.1;
        la = la / (4.0 * 64.0 * 16000.0);
        out[0] = (float)(lm + 10.0 * la + lr);
        out[1] = (float)lm;
        out[2] = (float)la;
    }
}

extern "C" void kernel_launch(void* const* d_in, const int* in_sizes, int n_in,
                              void* d_out, int out_size, void* d_ws, size_t ws_size,
                              hipStream_t stream) {
    const float* pred   = (const float*)d_in[0];
    const float* target = (const float*)d_in[1];
    const float* W      = (const float*)d_in[2];
    float* out = (float*)d_out;

    // workspace layout, total ~35.6 MB
    char* ws = (char*)d_ws;
    double*  cst  = (double*)ws;                              // 8192 B
    double*  fftP = (double*)(ws + 8192);                     // 2584*8 = 20672 B
    double2* emP  = (double2*)(ws + 28928);                   // 250*16 = 4000 B
    float2*  P    = (float2*)(ws + 33280);                    // 320*1024*8 = 2,621,440 B
    float2*  Tg   = (float2*)(ws + 2654720);                  // 20*1024*8 = 163,840 B
    unsigned short* H = (unsigned short*)(ws + 2818560);      // 8*16000*128*2 = 32,768,000 B

    hipLaunchKernelGGL(setup_kernel,  dim3(1), dim3(64), 0, stream, cst);
    hipLaunchKernelGGL(phase1_kernel, dim3(NB_FFT + NB_P1), dim3(256), 0, stream, pred, target, cst, P, fftP);
    hipLaunchKernelGGL(iir_scanA,     dim3(NGRP * 4), dim3(256), 0, stream, cst, P, Tg);
    hipLaunchKernelGGL(iir_pass2,     dim3(640), dim3(256), 0, stream, pred, target, cst, P, Tg, H);
    hipLaunchKernelGGL(embed_kernel,  dim3(NB_EMB), dim3(256), 0, stream, W, H, pred, target, emP);
    hipLaunchKernelGGL(finalize_kernel, dim3(1), dim3(256), 0, stream, fftP, emP, out);
}